// Round 1
// baseline (541.456 us; speedup 1.0000x reference)
//
#include <hip/hip_runtime.h>
#include <stdint.h>

#define IN_F  4096
#define OUT_F 4096
#define MROWS 8192            // 4 * 2048

typedef __bf16 bf16x8 __attribute__((ext_vector_type(8)));
typedef float  f32x4  __attribute__((ext_vector_type(4)));

// ---------------- numeric helpers (replicate reference rounding exactly) ---

// Round non-negative x to nearest E4M3 value; ties pick the LOWER value
// (reference: lo if x-lo <= hi-x). Grid arithmetic is exact in fp32.
__device__ __forceinline__ float e4m3_round_dev(float x) {
    x = fminf(x, 448.0f);                 // x >= 0 by construction (amax)
    float lo, hi;
    if (x < 0.015625f) {                  // below 2^-6: denormal grid, step 2^-9
        const float step = 0.001953125f;  // 2^-9
        lo = floorf(x * 512.0f) * step;
        hi = lo + step;
    } else {
        unsigned u = __float_as_uint(x);
        int E = (int)((u >> 23) & 0xFF) - 127;            // 2^E <= x < 2^(E+1)
        float step = __uint_as_float((unsigned)(E + 124) << 23);  // 2^(E-3)
        lo = floorf(x / step) * step;     // exact: x/step is exact scaling
        hi = lo + step;
    }
    return (x - lo <= hi - x) ? lo : hi;
}

// Decode e4m3 bit pattern
__device__ __forceinline__ float e4m3_decode_dev(int bits) {
    int e = (bits >> 3) & 15;
    int m = bits & 7;
    float mag;
    if (e == 0) mag = (float)m * 0.001953125f;  // m/8 * 2^-6
    else        mag = (1.0f + (float)m * 0.125f) * __uint_as_float((unsigned)(e + 120) << 23); // 2^(e-7)
    return (bits & 0x80) ? -mag : mag;
}

// Round to nearest E2M1; reference uses searchsorted(mids, a, side='right'):
// a exactly at a midpoint goes UP in magnitude -> strict '<' below.
__device__ __forceinline__ float fp4_round_dev(float y) {
    float a = fminf(fabsf(y), 6.0f);
    float v;
    if (a < 1.75f) {
        if (a < 0.75f) v = (a < 0.25f) ? 0.0f : 0.5f;
        else           v = (a < 1.25f) ? 1.0f : 1.5f;
    } else {
        if (a < 3.5f)  v = (a < 2.5f) ? 2.0f : 3.0f;
        else           v = (a < 5.0f) ? 4.0f : 6.0f;
    }
    return copysignf(v, y);
}

// Decode E2M1 code (4 bits: s e2 m1)
__device__ __forceinline__ float fp4_decode_dev(int c) {
    int e = (c >> 1) & 3, m = c & 1;
    float mag = (e == 0) ? 0.5f * (float)m
                         : (1.0f + 0.5f * (float)m) * __uint_as_float((unsigned)(e + 126) << 23); // 2^(e-1)
    return (c & 8) ? -mag : mag;
}

__device__ __forceinline__ unsigned pack_bf16x2(float a, float b) {
    // values are exactly representable in bf16 -> truncation is exact
    return (__float_as_uint(a) >> 16) | ((__float_as_uint(b) >> 16) << 16);
}

// ---------------- kernel 1: activation quant-dequant (scale-free) ----------
// Writes A'[m,k] = q * bscale  (bf16, exact). out = (isc*ws2) * A' @ W'^T.
__global__ __launch_bounds__(256) void quant_act_kernel(
    const float* __restrict__ x, const float* __restrict__ in_scale,
    unsigned short* __restrict__ Aq)
{
    int g = blockIdx.x * 256 + threadIdx.x;   // group id, 16 elems per group
    const float isc = in_scale[0];
    const float4* xp = (const float4*)x + (size_t)g * 4;
    float4 v0 = xp[0], v1 = xp[1], v2 = xp[2], v3 = xp[3];
    float f[16] = { v0.x, v0.y, v0.z, v0.w, v1.x, v1.y, v1.z, v1.w,
                    v2.x, v2.y, v2.z, v2.w, v3.x, v3.y, v3.z, v3.w };
    float amax = 0.0f;
    #pragma unroll
    for (int i = 0; i < 16; i++) amax = fmaxf(amax, fabsf(f[i]));

    float bscale = e4m3_round_dev(amax / (6.0f * isc));
    float eff = bscale * isc;
    float safe = (eff > 0.0f) ? eff : 1.0f;

    unsigned out[8];
    #pragma unroll
    for (int i = 0; i < 8; i++) {
        float a0 = fp4_round_dev(f[2 * i]     / safe) * bscale;
        float a1 = fp4_round_dev(f[2 * i + 1] / safe) * bscale;
        out[i] = pack_bf16x2(a0, a1);
    }
    uint4* dst = (uint4*)(Aq + (size_t)g * 16);
    dst[0] = make_uint4(out[0], out[1], out[2], out[3]);
    dst[1] = make_uint4(out[4], out[5], out[6], out[7]);
}

// ---------------- kernel 2: weight dequant (without ws2) -------------------
// Writes W'[n,k] = fp4 * bsW  (bf16, exact).
__global__ __launch_bounds__(256) void dequant_w_kernel(
    const int* __restrict__ wq, const int* __restrict__ wsb,
    unsigned short* __restrict__ Wd)
{
    int g = blockIdx.x * 256 + threadIdx.x;   // group id: n = g/256, k0 = (g%256)*16
    float scale = e4m3_decode_dev(wsb[g]);
    const int4* wp = (const int4*)wq + (size_t)g * 2;
    int4 b0 = wp[0], b1 = wp[1];
    int bytes[8] = { b0.x, b0.y, b0.z, b0.w, b1.x, b1.y, b1.z, b1.w };
    unsigned out[8];
    #pragma unroll
    for (int i = 0; i < 8; i++) {
        int by = bytes[i];
        float v0 = fp4_decode_dev(by & 15) * scale;         // element 2i
        float v1 = fp4_decode_dev((by >> 4) & 15) * scale;  // element 2i+1
        out[i] = pack_bf16x2(v0, v1);
    }
    uint4* dst = (uint4*)(Wd + (size_t)g * 16);
    dst[0] = make_uint4(out[0], out[1], out[2], out[3]);
    dst[1] = make_uint4(out[4], out[5], out[6], out[7]);
}

// ---------------- kernel 3: bf16 GEMM (m97 structure) ----------------------
// C[m,n] = s * sum_k A'[m,k] * W'[n,k],  s = input_scale * ws2
__device__ __forceinline__ void gload16(const void* g, void* l) {
    __builtin_amdgcn_global_load_lds((__attribute__((address_space(1))) void*)g,
                                     (__attribute__((address_space(3))) void*)l,
                                     16, 0, 0);
}

__global__ __launch_bounds__(256) void gemm_kernel(
    const unsigned short* __restrict__ A, const unsigned short* __restrict__ B,
    float* __restrict__ C, const float* __restrict__ isc,
    const float* __restrict__ ws2)
{
    __shared__ unsigned short As[128 * 32];   // 8 KB
    __shared__ unsigned short Bs[128 * 32];   // 8 KB

    const int tid  = threadIdx.x;
    const int lane = tid & 63;
    const int w    = tid >> 6;         // wave 0..3
    const int wm   = w >> 1, wn = w & 1;
    const int bm   = blockIdx.y, bn = blockIdx.x;

    // staging: 512 chunks of 16B per tile; chunk c: row = c>>2, k-chunk = c&3
    const int c0 = tid, c1 = tid + 256;
    const char* pA0 = (const char*)(A + (size_t)(bm * 128 + (c0 >> 2)) * IN_F + (c0 & 3) * 8);
    const char* pA1 = (const char*)(A + (size_t)(bm * 128 + (c1 >> 2)) * IN_F + (c1 & 3) * 8);
    const char* pB0 = (const char*)(B + (size_t)(bn * 128 + (c0 >> 2)) * IN_F + (c0 & 3) * 8);
    const char* pB1 = (const char*)(B + (size_t)(bn * 128 + (c1 >> 2)) * IN_F + (c1 & 3) * 8);
    char* lA0 = (char*)As + (w * 64) * 16;          // wave-uniform LDS bases
    char* lA1 = (char*)As + (256 + w * 64) * 16;
    char* lB0 = (char*)Bs + (w * 64) * 16;
    char* lB1 = (char*)Bs + (256 + w * 64) * 16;

    f32x4 acc[4][4];
    #pragma unroll
    for (int i = 0; i < 4; i++)
        #pragma unroll
        for (int j = 0; j < 4; j++)
            acc[i][j] = (f32x4){0.f, 0.f, 0.f, 0.f};

    const int l16 = lane & 15, quad = lane >> 4;
    const char* aBase = (const char*)As + (wm * 64 + l16) * 64 + quad * 16;
    const char* bBase = (const char*)Bs + (wn * 64 + l16) * 64 + quad * 16;

    for (int k = 0; k < IN_F; k += 32) {
        gload16(pA0, lA0); gload16(pA1, lA1);
        gload16(pB0, lB0); gload16(pB1, lB1);
        pA0 += 64; pA1 += 64; pB0 += 64; pB1 += 64;
        __syncthreads();   // drains vmcnt -> LDS tiles complete

        bf16x8 af[4], bf[4];
        #pragma unroll
        for (int i = 0; i < 4; i++) {
            af[i] = *(const bf16x8*)(aBase + i * 16 * 64);
            bf[i] = *(const bf16x8*)(bBase + i * 16 * 64);
        }
        #pragma unroll
        for (int i = 0; i < 4; i++)
            #pragma unroll
            for (int j = 0; j < 4; j++)
                acc[i][j] = __builtin_amdgcn_mfma_f32_16x16x32_bf16(af[i], bf[j], acc[i][j], 0, 0, 0);
        __syncthreads();   // compute done before next overwrite
    }

    const float s = isc[0] * ws2[0];
    #pragma unroll
    for (int i = 0; i < 4; i++) {
        int row0 = bm * 128 + wm * 64 + i * 16 + quad * 4;
        #pragma unroll
        for (int j = 0; j < 4; j++) {
            int col = bn * 128 + wn * 64 + j * 16 + l16;
            float* cp = C + (size_t)row0 * OUT_F + col;
            #pragma unroll
            for (int r = 0; r < 4; r++)
                cp[(size_t)r * OUT_F] = acc[i][j][r] * s;
        }
    }
}

// ---------------- launcher -------------------------------------------------
extern "C" void kernel_launch(void* const* d_in, const int* in_sizes, int n_in,
                              void* d_out, int out_size, void* d_ws, size_t ws_size,
                              hipStream_t stream) {
    const float* x   = (const float*)d_in[0];   // [8192, 4096] fp32
    const int*   wq  = (const int*)d_in[1];     // [4096, 2048] packed fp4 pairs
    const int*   wsb = (const int*)d_in[2];     // [4096, 256] e4m3 bits
    const float* ws2 = (const float*)d_in[3];   // scalar
    const float* isc = (const float*)d_in[4];   // scalar
    float* out = (float*)d_out;                 // [8192, 4096] fp32

    unsigned short* Aq = (unsigned short*)d_ws;                          // 64 MB
    unsigned short* Wd = (unsigned short*)d_ws + (size_t)MROWS * IN_F;   // 32 MB

    // 8192*4096/16 = 2,097,152 activation groups -> 8192 blocks of 256
    quant_act_kernel<<<8192, 256, 0, stream>>>(x, isc, Aq);
    // 4096*256 = 1,048,576 weight groups -> 4096 blocks of 256
    dequant_w_kernel<<<4096, 256, 0, stream>>>(wq, wsb, Wd);
    // 128x128 tiles: grid (N/128, M/128) = (32, 64)
    gemm_kernel<<<dim3(32, 64), 256, 0, stream>>>(Aq, Wd, out, isc, ws2);

    (void)in_sizes; (void)n_in; (void)out_size; (void)ws_size;
}

// Round 2
// 510.883 us; speedup vs baseline: 1.0598x; 1.0598x over previous
//
#include <hip/hip_runtime.h>
#include <stdint.h>

#define IN_F  4096
#define OUT_F 4096
#define MROWS 8192            // 4 * 2048

typedef __bf16 bf16x8 __attribute__((ext_vector_type(8)));
typedef float  f32x4  __attribute__((ext_vector_type(4)));

// ---------------- numeric helpers (replicate reference rounding) -----------

// Round non-negative x to nearest E4M3 value; ties pick the LOWER value
// (reference: lo if x-lo <= hi-x). All grid arithmetic exact (pow2 muls).
__device__ __forceinline__ float e4m3_round_dev(float x) {
    x = fminf(x, 448.0f);                 // x >= 0 by construction (amax)
    float lo, hi;
    if (x < 0.015625f) {                  // below 2^-6: denormal grid, step 2^-9
        lo = floorf(x * 512.0f) * 0.001953125f;
        hi = lo + 0.001953125f;
    } else {
        unsigned u = __float_as_uint(x);
        int E = (int)((u >> 23) & 0xFF) - 127;                    // 2^E <= x < 2^(E+1)
        float step  = __uint_as_float((unsigned)(E + 124) << 23); // 2^(E-3)
        float istep = __uint_as_float((unsigned)(130 - E) << 23); // 2^(3-E), exact
        lo = floorf(x * istep) * step;    // exact pow2 scaling
        hi = lo + step;
    }
    return (x - lo <= hi - x) ? lo : hi;
}

__device__ __forceinline__ float e4m3_decode_dev(int bits) {
    int e = (bits >> 3) & 15;
    int m = bits & 7;
    float mag;
    if (e == 0) mag = (float)m * 0.001953125f;  // m/8 * 2^-6
    else        mag = (1.0f + (float)m * 0.125f) * __uint_as_float((unsigned)(e + 120) << 23); // 2^(e-7)
    return (bits & 0x80) ? -mag : mag;
}

// Round to nearest E2M1; ties go UP in magnitude (searchsorted side='right').
__device__ __forceinline__ float fp4_round_dev(float y) {
    float a = fminf(fabsf(y), 6.0f);
    float v;
    if (a < 1.75f) {
        if (a < 0.75f) v = (a < 0.25f) ? 0.0f : 0.5f;
        else           v = (a < 1.25f) ? 1.0f : 1.5f;
    } else {
        if (a < 3.5f)  v = (a < 2.5f) ? 2.0f : 3.0f;
        else           v = (a < 5.0f) ? 4.0f : 6.0f;
    }
    return copysignf(v, y);
}

__device__ __forceinline__ float fp4_decode_dev(int c) {
    int e = (c >> 1) & 3, m = c & 1;
    float mag = (e == 0) ? 0.5f * (float)m
                         : (1.0f + 0.5f * (float)m) * __uint_as_float((unsigned)(e + 126) << 23); // 2^(e-1)
    return (c & 8) ? -mag : mag;
}

__device__ __forceinline__ unsigned pack_bf16x2(float a, float b) {
    // values are exactly representable in bf16 -> truncation is exact
    return (__float_as_uint(a) >> 16) | ((__float_as_uint(b) >> 16) << 16);
}

// ---------------- kernel 1: activation quant-dequant (scale-free) ----------
// Writes A'[m,k] = q * bscale  (bf16, exact). out = (isc*ws2) * A' @ W'^T.
__global__ __launch_bounds__(256) void quant_act_kernel(
    const float* __restrict__ x, const float* __restrict__ in_scale,
    unsigned short* __restrict__ Aq)
{
    int g = blockIdx.x * 256 + threadIdx.x;   // group id, 16 elems per group
    const float isc = in_scale[0];
    const float4* xp = (const float4*)x + (size_t)g * 4;
    float4 v0 = xp[0], v1 = xp[1], v2 = xp[2], v3 = xp[3];
    float f[16] = { v0.x, v0.y, v0.z, v0.w, v1.x, v1.y, v1.z, v1.w,
                    v2.x, v2.y, v2.z, v2.w, v3.x, v3.y, v3.z, v3.w };
    float amax = 0.0f;
    #pragma unroll
    for (int i = 0; i < 16; i++) amax = fmaxf(amax, fabsf(f[i]));

    float bscale = e4m3_round_dev(amax / (6.0f * isc));   // one IEEE div
    float eff = bscale * isc;
    float safe = (eff > 0.0f) ? eff : 1.0f;
    float inv = 1.0f / safe;                              // one IEEE div

    unsigned out[8];
    #pragma unroll
    for (int i = 0; i < 8; i++) {
        float a0 = fp4_round_dev(f[2 * i]     * inv) * bscale;
        float a1 = fp4_round_dev(f[2 * i + 1] * inv) * bscale;
        out[i] = pack_bf16x2(a0, a1);
    }
    uint4* dst = (uint4*)(Aq + (size_t)g * 16);
    dst[0] = make_uint4(out[0], out[1], out[2], out[3]);
    dst[1] = make_uint4(out[4], out[5], out[6], out[7]);
}

// ---------------- kernel 2: weight dequant (without ws2) -------------------
// Writes W'[n,k] = fp4 * bsW  (bf16, exact).
__global__ __launch_bounds__(256) void dequant_w_kernel(
    const int* __restrict__ wq, const int* __restrict__ wsb,
    unsigned short* __restrict__ Wd)
{
    int g = blockIdx.x * 256 + threadIdx.x;   // group id: n = g/256, k0 = (g%256)*16
    float scale = e4m3_decode_dev(wsb[g]);
    const int4* wp = (const int4*)wq + (size_t)g * 2;
    int4 b0 = wp[0], b1 = wp[1];
    int bytes[8] = { b0.x, b0.y, b0.z, b0.w, b1.x, b1.y, b1.z, b1.w };
    unsigned out[8];
    #pragma unroll
    for (int i = 0; i < 8; i++) {
        int by = bytes[i];
        float v0 = fp4_decode_dev(by & 15) * scale;         // element 2i
        float v1 = fp4_decode_dev((by >> 4) & 15) * scale;  // element 2i+1
        out[i] = pack_bf16x2(v0, v1);
    }
    uint4* dst = (uint4*)(Wd + (size_t)g * 16);
    dst[0] = make_uint4(out[0], out[1], out[2], out[3]);
    dst[1] = make_uint4(out[4], out[5], out[6], out[7]);
}

// ---------------- kernel 3: bf16 GEMM, BK=64 + XOR-swizzled LDS ------------
// C[m,n] = s * sum_k A'[m,k] * W'[n,k],  s = input_scale * ws2
//
// LDS tile: 128 rows x 64 cols bf16 (16 KB). 16B chunk (row, kc), kc=0..7,
// stored at LDS position row*8 + (kc ^ (row&7)).  The XOR spreads fragment
// reads to 2 lanes/bank (free) instead of 16-way (128B-stride pathological).
// global_load_lds requires lane-contiguous LDS, so the swizzle is applied on
// the global-source side: the lane at LDS pos c fetches kc = (c&7)^(row&7).
__device__ __forceinline__ void gload16(const void* g, void* l) {
    __builtin_amdgcn_global_load_lds((__attribute__((address_space(1))) void*)g,
                                     (__attribute__((address_space(3))) void*)l,
                                     16, 0, 0);
}

__global__ __launch_bounds__(256) void gemm_kernel(
    const unsigned short* __restrict__ A, const unsigned short* __restrict__ B,
    float* __restrict__ C, const float* __restrict__ isc,
    const float* __restrict__ ws2)
{
    __shared__ unsigned short As[128 * 64];   // 16 KB
    __shared__ unsigned short Bs[128 * 64];   // 16 KB

    const int tid  = threadIdx.x;
    const int lane = tid & 63;
    const int w    = tid >> 6;         // wave 0..3
    const int wm   = w >> 1, wn = w & 1;
    const int bm   = blockIdx.y, bn = blockIdx.x;

    // staging: 1024 chunks of 16B per tile; thread handles c = tid + 256*i
    const char* pA[4]; const char* pB[4];
    char* lA[4]; char* lB[4];
    #pragma unroll
    for (int i = 0; i < 4; i++) {
        int c   = tid + 256 * i;
        int row = c >> 3;
        int kc  = (c & 7) ^ (row & 7);      // XOR swizzle (source side)
        pA[i] = (const char*)(A + (size_t)(bm * 128 + row) * IN_F + kc * 8);
        pB[i] = (const char*)(B + (size_t)(bn * 128 + row) * IN_F + kc * 8);
        lA[i] = (char*)As + c * 16;
        lB[i] = (char*)Bs + c * 16;
    }

    f32x4 acc[4][4];
    #pragma unroll
    for (int i = 0; i < 4; i++)
        #pragma unroll
        for (int j = 0; j < 4; j++)
            acc[i][j] = (f32x4){0.f, 0.f, 0.f, 0.f};

    const int l16 = lane & 15, quad = lane >> 4;
    const int x7  = l16 & 7;
    const char* aRow = (const char*)As + (wm * 64 + l16) * 128;
    const char* bRow = (const char*)Bs + (wn * 64 + l16) * 128;

    for (int k = 0; k < IN_F; k += 64) {
        #pragma unroll
        for (int i = 0; i < 4; i++) {
            gload16(pA[i], lA[i]); gload16(pB[i], lB[i]);
            pA[i] += 128; pB[i] += 128;
        }
        __syncthreads();   // drains vmcnt -> LDS tiles complete

        #pragma unroll
        for (int h = 0; h < 2; h++) {
            const int sw = (((h << 2) | quad) ^ x7) * 16;   // swizzled 16B chunk
            bf16x8 af[4], bf[4];
            #pragma unroll
            for (int i = 0; i < 4; i++) {
                af[i] = *(const bf16x8*)(aRow + i * 16 * 128 + sw);
                bf[i] = *(const bf16x8*)(bRow + i * 16 * 128 + sw);
            }
            #pragma unroll
            for (int i = 0; i < 4; i++)
                #pragma unroll
                for (int j = 0; j < 4; j++)
                    acc[i][j] = __builtin_amdgcn_mfma_f32_16x16x32_bf16(af[i], bf[j], acc[i][j], 0, 0, 0);
        }
        __syncthreads();   // compute done before next overwrite
    }

    const float s = isc[0] * ws2[0];
    #pragma unroll
    for (int i = 0; i < 4; i++) {
        int row0 = bm * 128 + wm * 64 + i * 16 + quad * 4;
        #pragma unroll
        for (int j = 0; j < 4; j++) {
            int col = bn * 128 + wn * 64 + j * 16 + l16;
            float* cp = C + (size_t)row0 * OUT_F + col;
            #pragma unroll
            for (int r = 0; r < 4; r++)
                cp[(size_t)r * OUT_F] = acc[i][j][r] * s;
        }
    }
}

// ---------------- launcher -------------------------------------------------
extern "C" void kernel_launch(void* const* d_in, const int* in_sizes, int n_in,
                              void* d_out, int out_size, void* d_ws, size_t ws_size,
                              hipStream_t stream) {
    const float* x   = (const float*)d_in[0];   // [8192, 4096] fp32
    const int*   wq  = (const int*)d_in[1];     // [4096, 2048] packed fp4 pairs
    const int*   wsb = (const int*)d_in[2];     // [4096, 256] e4m3 bits
    const float* ws2 = (const float*)d_in[3];   // scalar
    const float* isc = (const float*)d_in[4];   // scalar
    float* out = (float*)d_out;                 // [8192, 4096] fp32

    unsigned short* Aq = (unsigned short*)d_ws;                          // 64 MB
    unsigned short* Wd = (unsigned short*)d_ws + (size_t)MROWS * IN_F;   // 32 MB

    quant_act_kernel<<<8192, 256, 0, stream>>>(x, isc, Aq);
    dequant_w_kernel<<<4096, 256, 0, stream>>>(wq, wsb, Wd);
    gemm_kernel<<<dim3(32, 64), 256, 0, stream>>>(Aq, Wd, out, isc, ws2);

    (void)in_sizes; (void)n_in; (void)out_size; (void)ws_size;
}

// Round 3
// 499.915 us; speedup vs baseline: 1.0831x; 1.0219x over previous
//
#include <hip/hip_runtime.h>
#include <stdint.h>

#define IN_F  4096
#define OUT_F 4096
#define MROWS 8192            // 4 * 2048

typedef __bf16 bf16x8 __attribute__((ext_vector_type(8)));
typedef float  f32x4  __attribute__((ext_vector_type(4)));

// ---------------- numeric helpers (replicate reference rounding) -----------

// Round non-negative x to nearest E4M3 value; ties pick the LOWER value
// (reference: lo if x-lo <= hi-x). All grid arithmetic exact (pow2 muls).
__device__ __forceinline__ float e4m3_round_dev(float x) {
    x = fminf(x, 448.0f);                 // x >= 0 by construction (amax)
    float lo, hi;
    if (x < 0.015625f) {                  // below 2^-6: denormal grid, step 2^-9
        lo = floorf(x * 512.0f) * 0.001953125f;
        hi = lo + 0.001953125f;
    } else {
        unsigned u = __float_as_uint(x);
        int E = (int)((u >> 23) & 0xFF) - 127;                    // 2^E <= x < 2^(E+1)
        float step  = __uint_as_float((unsigned)(E + 124) << 23); // 2^(E-3)
        float istep = __uint_as_float((unsigned)(130 - E) << 23); // 2^(3-E), exact
        lo = floorf(x * istep) * step;    // exact pow2 scaling
        hi = lo + step;
    }
    return (x - lo <= hi - x) ? lo : hi;
}

__device__ __forceinline__ float e4m3_decode_dev(int bits) {
    int e = (bits >> 3) & 15;
    int m = bits & 7;
    float mag;
    if (e == 0) mag = (float)m * 0.001953125f;  // m/8 * 2^-6
    else        mag = (1.0f + (float)m * 0.125f) * __uint_as_float((unsigned)(e + 120) << 23); // 2^(e-7)
    return (bits & 0x80) ? -mag : mag;
}

// Round to nearest E2M1; ties go UP in magnitude (searchsorted side='right').
__device__ __forceinline__ float fp4_round_dev(float y) {
    float a = fminf(fabsf(y), 6.0f);
    float v;
    if (a < 1.75f) {
        if (a < 0.75f) v = (a < 0.25f) ? 0.0f : 0.5f;
        else           v = (a < 1.25f) ? 1.0f : 1.5f;
    } else {
        if (a < 3.5f)  v = (a < 2.5f) ? 2.0f : 3.0f;
        else           v = (a < 5.0f) ? 4.0f : 6.0f;
    }
    return copysignf(v, y);
}

__device__ __forceinline__ float fp4_decode_dev(int c) {
    int e = (c >> 1) & 3, m = c & 1;
    float mag = (e == 0) ? 0.5f * (float)m
                         : (1.0f + 0.5f * (float)m) * __uint_as_float((unsigned)(e + 126) << 23); // 2^(e-1)
    return (c & 8) ? -mag : mag;
}

__device__ __forceinline__ unsigned pack_bf16x2(float a, float b) {
    // values are exactly representable in bf16 -> truncation is exact
    return (__float_as_uint(a) >> 16) | ((__float_as_uint(b) >> 16) << 16);
}

// ---------------- kernel 1: activation quant-dequant (lane-parallel) -------
// One thread per 4 elements; a 16-group = 4 adjacent lanes. Fully coalesced:
// float4 load 16B/lane, uint2 store 8B/lane. amax via 2x shfl_xor.
// Writes A'[m,k] = q * bscale (bf16, exact). out = (isc*ws2) * A' @ W'^T.
__global__ __launch_bounds__(256) void quant_act_kernel(
    const float* __restrict__ x, const float* __restrict__ in_scale,
    unsigned short* __restrict__ Aq)
{
    int t = blockIdx.x * 256 + threadIdx.x;   // thread id; 4 elems each
    const float isc = in_scale[0];
    float4 v = ((const float4*)x)[t];

    float a = fmaxf(fmaxf(fabsf(v.x), fabsf(v.y)), fmaxf(fabsf(v.z), fabsf(v.w)));
    a = fmaxf(a, __shfl_xor(a, 1));
    a = fmaxf(a, __shfl_xor(a, 2));           // group (4 lanes) amax

    float bscale = e4m3_round_dev(a / (6.0f * isc));  // IEEE div, as reference
    float eff = bscale * isc;
    float safe = (eff > 0.0f) ? eff : 1.0f;
    float inv = 1.0f / safe;                          // IEEE div

    unsigned o0 = pack_bf16x2(fp4_round_dev(v.x * inv) * bscale,
                              fp4_round_dev(v.y * inv) * bscale);
    unsigned o1 = pack_bf16x2(fp4_round_dev(v.z * inv) * bscale,
                              fp4_round_dev(v.w * inv) * bscale);
    ((uint2*)Aq)[t] = make_uint2(o0, o1);
}

// ---------------- kernel 2: weight dequant (lane-parallel) -----------------
// One thread per 4 packed int32 (= 8 fp4 values). int4 load 16B/lane,
// uint4 store 16B/lane, both contiguous. Scale idx = t>>1 (2 lanes share).
// Writes W'[n,k] = fp4 * bsW (bf16, exact).
__global__ __launch_bounds__(256) void dequant_w_kernel(
    const int* __restrict__ wq, const int* __restrict__ wsb,
    unsigned short* __restrict__ Wd)
{
    int t = blockIdx.x * 256 + threadIdx.x;
    float scale = e4m3_decode_dev(wsb[t >> 1]);
    int4 b = ((const int4*)wq)[t];
    int bytes[4] = { b.x, b.y, b.z, b.w };
    unsigned out[4];
    #pragma unroll
    for (int i = 0; i < 4; i++) {
        int by = bytes[i];
        float v0 = fp4_decode_dev(by & 15) * scale;
        float v1 = fp4_decode_dev((by >> 4) & 15) * scale;
        out[i] = pack_bf16x2(v0, v1);
    }
    ((uint4*)Wd)[t] = make_uint4(out[0], out[1], out[2], out[3]);
}

// ---------------- kernel 3: bf16 GEMM, BK=64 + XOR-swizzled LDS ------------
// C[m,n] = s * sum_k A'[m,k] * W'[n,k],  s = input_scale * ws2
//
// LDS tile: 128 rows x 64 cols bf16 (16 KB). 16B chunk (row, kc), kc=0..7,
// stored at LDS position row*8 + (kc ^ (row&7)). XOR spreads fragment reads
// to 2 lanes/bank (free). global_load_lds requires lane-contiguous LDS, so
// the swizzle is applied on the global-source side.
__device__ __forceinline__ void gload16(const void* g, void* l) {
    __builtin_amdgcn_global_load_lds((__attribute__((address_space(1))) void*)g,
                                     (__attribute__((address_space(3))) void*)l,
                                     16, 0, 0);
}

__global__ __launch_bounds__(256) void gemm_kernel(
    const unsigned short* __restrict__ A, const unsigned short* __restrict__ B,
    float* __restrict__ C, const float* __restrict__ isc,
    const float* __restrict__ ws2)
{
    __shared__ unsigned short As[128 * 64];   // 16 KB
    __shared__ unsigned short Bs[128 * 64];   // 16 KB

    const int tid  = threadIdx.x;
    const int lane = tid & 63;
    const int w    = tid >> 6;         // wave 0..3
    const int wm   = w >> 1, wn = w & 1;
    const int bm   = blockIdx.y, bn = blockIdx.x;

    // staging: 1024 chunks of 16B per tile; thread handles c = tid + 256*i
    const char* pA[4]; const char* pB[4];
    char* lA[4]; char* lB[4];
    #pragma unroll
    for (int i = 0; i < 4; i++) {
        int c   = tid + 256 * i;
        int row = c >> 3;
        int kc  = (c & 7) ^ (row & 7);      // XOR swizzle (source side)
        pA[i] = (const char*)(A + (size_t)(bm * 128 + row) * IN_F + kc * 8);
        pB[i] = (const char*)(B + (size_t)(bn * 128 + row) * IN_F + kc * 8);
        lA[i] = (char*)As + c * 16;
        lB[i] = (char*)Bs + c * 16;
    }

    f32x4 acc[4][4];
    #pragma unroll
    for (int i = 0; i < 4; i++)
        #pragma unroll
        for (int j = 0; j < 4; j++)
            acc[i][j] = (f32x4){0.f, 0.f, 0.f, 0.f};

    const int l16 = lane & 15, quad = lane >> 4;
    const int x7  = l16 & 7;
    const char* aRow = (const char*)As + (wm * 64 + l16) * 128;
    const char* bRow = (const char*)Bs + (wn * 64 + l16) * 128;

    for (int k = 0; k < IN_F; k += 64) {
        #pragma unroll
        for (int i = 0; i < 4; i++) {
            gload16(pA[i], lA[i]); gload16(pB[i], lB[i]);
            pA[i] += 128; pB[i] += 128;
        }
        __syncthreads();   // drains vmcnt -> LDS tiles complete

        #pragma unroll
        for (int h = 0; h < 2; h++) {
            const int sw = (((h << 2) | quad) ^ x7) * 16;   // swizzled 16B chunk
            bf16x8 af[4], bf[4];
            #pragma unroll
            for (int i = 0; i < 4; i++) {
                af[i] = *(const bf16x8*)(aRow + i * 16 * 128 + sw);
                bf[i] = *(const bf16x8*)(bRow + i * 16 * 128 + sw);
            }
            #pragma unroll
            for (int i = 0; i < 4; i++)
                #pragma unroll
                for (int j = 0; j < 4; j++)
                    acc[i][j] = __builtin_amdgcn_mfma_f32_16x16x32_bf16(af[i], bf[j], acc[i][j], 0, 0, 0);
        }
        __syncthreads();   // compute done before next overwrite
    }

    const float s = isc[0] * ws2[0];
    #pragma unroll
    for (int i = 0; i < 4; i++) {
        int row0 = bm * 128 + wm * 64 + i * 16 + quad * 4;
        #pragma unroll
        for (int j = 0; j < 4; j++) {
            int col = bn * 128 + wn * 64 + j * 16 + l16;
            float* cp = C + (size_t)row0 * OUT_F + col;
            #pragma unroll
            for (int r = 0; r < 4; r++)
                cp[(size_t)r * OUT_F] = acc[i][j][r] * s;
        }
    }
}

// ---------------- launcher -------------------------------------------------
extern "C" void kernel_launch(void* const* d_in, const int* in_sizes, int n_in,
                              void* d_out, int out_size, void* d_ws, size_t ws_size,
                              hipStream_t stream) {
    const float* x   = (const float*)d_in[0];   // [8192, 4096] fp32
    const int*   wq  = (const int*)d_in[1];     // [4096, 2048] packed fp4 pairs
    const int*   wsb = (const int*)d_in[2];     // [4096, 256] e4m3 bits
    const float* ws2 = (const float*)d_in[3];   // scalar
    const float* isc = (const float*)d_in[4];   // scalar
    float* out = (float*)d_out;                 // [8192, 4096] fp32

    unsigned short* Aq = (unsigned short*)d_ws;                          // 64 MB
    unsigned short* Wd = (unsigned short*)d_ws + (size_t)MROWS * IN_F;   // 32 MB

    // 8192*4096/4 = 8,388,608 threads -> 32768 blocks of 256
    quant_act_kernel<<<32768, 256, 0, stream>>>(x, isc, Aq);
    // 4096*2048/4 = 2,097,152 threads -> 8192 blocks of 256
    dequant_w_kernel<<<8192, 256, 0, stream>>>(wq, wsb, Wd);
    gemm_kernel<<<dim3(32, 64), 256, 0, stream>>>(Aq, Wd, out, isc, ws2);

    (void)in_sizes; (void)n_in; (void)out_size; (void)ws_size;
}